// Round 1
// 417.308 us; speedup vs baseline: 1.0375x; 1.0375x over previous
//
#include <hip/hip_runtime.h>
#include <hip/hip_bf16.h>
#include <math.h>

// Problem constants (fixed by reference)
#define BATCH 2
#define SEQ   2048
#define DMODEL 2048
#define NHEADS 16
#define HDIM  128
#define MROWS (BATCH * SEQ)   // 4096

typedef __attribute__((ext_vector_type(8))) short short8;
typedef __attribute__((ext_vector_type(8))) unsigned short ushort8;
typedef __attribute__((ext_vector_type(4))) float f32x4;

static __device__ __forceinline__ unsigned short f2bf(float x) {
    __hip_bfloat16 h = __float2bfloat16(x);
    return __builtin_bit_cast(unsigned short, h);
}

static __device__ __forceinline__ void async_load16(const void* g, void* l) {
    __builtin_amdgcn_global_load_lds(
        (const __attribute__((address_space(1))) unsigned int*)g,
        (__attribute__((address_space(3))) unsigned int*)l, 16, 0, 0);
}

// ---------------------------------------------------------------------------
// fp32 -> bf16 elementwise convert (x)
// ---------------------------------------------------------------------------
__global__ __launch_bounds__(256) void convert_bf16_kernel(
    const float* __restrict__ in, unsigned short* __restrict__ out, int n)
{
    const int idx = (blockIdx.x * 256 + threadIdx.x) * 4;
    if (idx < n) {
        const float4 v = *(const float4*)(in + idx);
        ushort4 u;
        u.x = f2bf(v.x); u.y = f2bf(v.y); u.z = f2bf(v.z); u.w = f2bf(v.w);
        *(ushort4*)(out + idx) = u;
    }
}

// ---------------------------------------------------------------------------
// Fused transpose of wq,wk,wv: [K,N] fp32 -> [N,K] bf16 into 3 Wt slots.
// ---------------------------------------------------------------------------
__global__ __launch_bounds__(256) void transpose3_bf16_kernel(
    const float* __restrict__ w0, const float* __restrict__ w1,
    const float* __restrict__ w2, unsigned short* __restrict__ WtAll)
{
    const float* W = blockIdx.z == 0 ? w0 : (blockIdx.z == 1 ? w1 : w2);
    unsigned short* Wt = WtAll + (size_t)blockIdx.z * DMODEL * DMODEL;

    __shared__ float T[64][65];
    const int tid = threadIdx.x;
    const int tr  = tid >> 4;
    const int tc4 = (tid & 15) * 4;
    const int k0 = blockIdx.y * 64;
    const int n0 = blockIdx.x * 64;

    #pragma unroll
    for (int i = 0; i < 4; ++i) {
        const int kr = i * 16 + tr;
        const float4 v = *(const float4*)(W + (size_t)(k0 + kr) * DMODEL + n0 + tc4);
        T[kr][tc4 + 0] = v.x; T[kr][tc4 + 1] = v.y;
        T[kr][tc4 + 2] = v.z; T[kr][tc4 + 3] = v.w;
    }
    __syncthreads();
    #pragma unroll
    for (int i = 0; i < 4; ++i) {
        const int nr = i * 16 + tr;
        ushort4 u;
        u.x = f2bf(T[tc4 + 0][nr]); u.y = f2bf(T[tc4 + 1][nr]);
        u.z = f2bf(T[tc4 + 2][nr]); u.w = f2bf(T[tc4 + 3][nr]);
        *(ushort4*)(Wt + (size_t)(n0 + nr) * DMODEL + k0 + tc4) = u;
    }
}

// single transpose (for wo)
__global__ __launch_bounds__(256) void transpose_bf16_kernel(
    const float* __restrict__ W, unsigned short* __restrict__ Wt, int K, int N)
{
    __shared__ float T[64][65];
    const int tid = threadIdx.x;
    const int tr  = tid >> 4;
    const int tc4 = (tid & 15) * 4;
    const int k0 = blockIdx.y * 64;
    const int n0 = blockIdx.x * 64;

    #pragma unroll
    for (int i = 0; i < 4; ++i) {
        const int kr = i * 16 + tr;
        const float4 v = *(const float4*)(W + (size_t)(k0 + kr) * N + n0 + tc4);
        T[kr][tc4 + 0] = v.x; T[kr][tc4 + 1] = v.y;
        T[kr][tc4 + 2] = v.z; T[kr][tc4 + 3] = v.w;
    }
    __syncthreads();
    #pragma unroll
    for (int i = 0; i < 4; ++i) {
        const int nr = i * 16 + tr;
        ushort4 u;
        u.x = f2bf(T[tc4 + 0][nr]); u.y = f2bf(T[tc4 + 1][nr]);
        u.z = f2bf(T[tc4 + 2][nr]); u.w = f2bf(T[tc4 + 3][nr]);
        *(ushort4*)(Wt + (size_t)(n0 + nr) * K + k0 + tc4) = u;
    }
}

// ---------------------------------------------------------------------------
// Fused QKV GEMM — 256x256 tile, BK=64, 8 waves (2M x 4N), 8-phase schedule
// with counted vmcnt(6) (T3+T4), st-style XOR granule swizzle (T2, both-sides:
// pre-swizzled global source + swizzled ds_read), setprio around MFMA (T5).
//
// LDS: 2 buffers x (A 32KB + B 32KB) = 128 KB. Staging unit = 8KB (64 rows x
// 64 cols bf16) = 1 global_load_lds(16B) per thread. Race-freedom by
// construction:
//   - B frags are fully register-prefetched in phase 1 -> B region of the
//     current buffer is recycled (staged for tile t+2) in phases 2-3.
//   - A quarters A0/A2 (rows 0-63 / 128-191) are last ds_read in phase 2 ->
//     staged for t+2 in phase 4; A1/A3 last read in phase 4 -> staged for
//     t+1 at next tile's phase 1 (after the boundary barrier).
//   Every overwrite is therefore separated from the last read of the region
//   by that phase's lgkmcnt(0) + a barrier (issue-after-completion).
// Boundary wait: vmcnt(6) at phase 4 (6 loads = 3 units of tile t+2 stay in
// flight across the barrier; everything older — i.e. all of tile t+1 — has
// landed). Never drains to 0 in steady state.
// ---------------------------------------------------------------------------
__global__ __launch_bounds__(512, 2) void qkv_gemm256_kernel(
    const unsigned short* __restrict__ A, const unsigned short* __restrict__ WtAll,
    const float* __restrict__ bq, const float* __restrict__ bk,
    const float* __restrict__ bv,
    unsigned short* __restrict__ Qb, unsigned short* __restrict__ Kb,
    unsigned short* __restrict__ Vt)
{
    constexpr int K  = DMODEL;   // 2048
    constexpr int NT = K / 64;   // 32 K-tiles

    __shared__ __align__(16) unsigned short As[2][256 * 64];
    __shared__ __align__(16) unsigned short Bs[2][256 * 64];

    const int tid  = threadIdx.x;
    const int lane = tid & 63;
    const int wave = tid >> 6;      // 0..7
    const int ln15 = lane & 15;
    const int quad = lane >> 4;
    const int wr   = wave >> 2;     // 0..1  (M)
    const int wc   = wave & 3;      // 0..3  (N)

    const int bm   = blockIdx.y * 256;
    const int bn   = blockIdx.x * 256;     // 0..5888
    const int widx = bn >> 11;             // 0=Q 1=K 2=V
    const int bnl  = bn & 2047;

    const unsigned short* Bt = WtAll + (size_t)widx * DMODEL * DMODEL;
    const float* bias = widx == 0 ? bq : (widx == 1 ? bk : bv);

    // ---- staging: thread -> (row sr within unit, swizzled source granule) ----
    const int sr = tid >> 3;                 // 0..63
    const int sg = (tid & 7) ^ (sr & 7);     // XOR swizzle (involution)
    const unsigned short* Ag = A  + (size_t)(bm  + sr) * K + sg * 8;
    const unsigned short* Bg = Bt + (size_t)(bnl + sr) * K + sg * 8;

    // ---- ds_read offsets (ushort units); physical granule = logical ^ (row&7)
    const int swz0 = ((0 + quad) ^ (ln15 & 7)) * 8;   // ks=0 granules 0..3
    const int swz1 = ((4 + quad) ^ (ln15 & 7)) * 8;   // ks=1 granules 4..7
    const int arow = (wr * 128 + ln15) * 64;          // + mp*1024
    const int brow = (wc * 64  + ln15) * 64;          // + np*1024

#define STAGE_A(c, q, k0) async_load16(Ag + (size_t)(q) * 64 * K + (k0), \
                                       &As[c][(q) * 4096 + wave * 512])
#define STAGE_B(c, q, k0) async_load16(Bg + (size_t)(q) * 64 * K + (k0), \
                                       &Bs[c][(q) * 4096 + wave * 512])

    f32x4 acc[8][4];
    #pragma unroll
    for (int i = 0; i < 8; ++i)
        #pragma unroll
        for (int j = 0; j < 4; ++j) acc[i][j] = (f32x4){0.f, 0.f, 0.f, 0.f};

    // ---- prologue: tile 0 full (8 units), tile 1 first 6 units ----
    STAGE_A(0, 0, 0); STAGE_A(0, 1, 0); STAGE_A(0, 2, 0); STAGE_A(0, 3, 0);
    STAGE_B(0, 0, 0); STAGE_B(0, 1, 0); STAGE_B(0, 2, 0); STAGE_B(0, 3, 0);
    STAGE_B(1, 0, 64); STAGE_B(1, 1, 64); STAGE_B(1, 2, 64); STAGE_B(1, 3, 64);
    STAGE_A(1, 0, 64); STAGE_A(1, 2, 64);
    asm volatile("s_waitcnt vmcnt(6)" ::: "memory");   // tile 0 landed
    __builtin_amdgcn_s_barrier();

    short8 bfr[4][2];
    short8 af[2][2];

#define READ_A(MLO)                                                           \
    af[0][0] = *(const short8*)(Ac + arow + (MLO) * 1024 + swz0);             \
    af[0][1] = *(const short8*)(Ac + arow + (MLO) * 1024 + swz1);             \
    af[1][0] = *(const short8*)(Ac + arow + (MLO) * 1024 + 1024 + swz0);      \
    af[1][1] = *(const short8*)(Ac + arow + (MLO) * 1024 + 1024 + swz1);

#define PHASE_MFMA(MLO)                                                       \
    __builtin_amdgcn_s_barrier();                                             \
    asm volatile("s_waitcnt lgkmcnt(0)" ::: "memory");                        \
    __builtin_amdgcn_sched_barrier(0);                                        \
    __builtin_amdgcn_s_setprio(1);                                            \
    _Pragma("unroll")                                                         \
    for (int ks = 0; ks < 2; ++ks)                                            \
        _Pragma("unroll")                                                     \
        for (int mt = 0; mt < 2; ++mt)                                        \
            _Pragma("unroll")                                                 \
            for (int nt = 0; nt < 4; ++nt)                                    \
                acc[(MLO) + mt][nt] = __builtin_amdgcn_mfma_f32_16x16x32_bf16(\
                    af[mt][ks], bfr[nt][ks], acc[(MLO) + mt][nt], 0, 0, 0);   \
    __builtin_amdgcn_s_setprio(0);

    #pragma unroll 2
    for (int t = 0; t < NT; ++t) {
        const int c  = t & 1;
        const int k1 = (t + 1) * 64;
        const int k2 = (t + 2) * 64;
        const unsigned short* Ac = As[c];
        const unsigned short* Bc = Bs[c];

        // ---- phase 1: all 8 B frags + A m0-1; stage A1,A3 of t+1 ----
        #pragma unroll
        for (int np = 0; np < 4; ++np) {
            bfr[np][0] = *(const short8*)(Bc + brow + np * 1024 + swz0);
            bfr[np][1] = *(const short8*)(Bc + brow + np * 1024 + swz1);
        }
        READ_A(0)
        if (t + 1 < NT) { STAGE_A(c ^ 1, 1, k1); STAGE_A(c ^ 1, 3, k1); }
        PHASE_MFMA(0)
        __builtin_amdgcn_s_barrier();

        // ---- phase 2: A m2-3; stage B0,B1 of t+2 (B fully read in ph1) ----
        READ_A(2)
        if (t + 2 < NT) { STAGE_B(c, 0, k2); STAGE_B(c, 1, k2); }
        PHASE_MFMA(2)
        __builtin_amdgcn_s_barrier();

        // ---- phase 3: A m4-5; stage B2,B3 of t+2 ----
        READ_A(4)
        if (t + 2 < NT) { STAGE_B(c, 2, k2); STAGE_B(c, 3, k2); }
        PHASE_MFMA(4)
        __builtin_amdgcn_s_barrier();

        // ---- phase 4: A m6-7; stage A0,A2 of t+2 (last read in ph2);
        //      counted vmcnt -> tile t+1 fully landed, 6 loads stay in flight
        READ_A(6)
        if (t + 2 < NT) { STAGE_A(c, 0, k2); STAGE_A(c, 2, k2); }
        PHASE_MFMA(6)
        if (t + 2 < NT) { asm volatile("s_waitcnt vmcnt(6)" ::: "memory"); }
        else            { asm volatile("s_waitcnt vmcnt(0)" ::: "memory"); }
        __builtin_amdgcn_s_barrier();
    }

#undef STAGE_A
#undef STAGE_B
#undef READ_A
#undef PHASE_MFMA

    // ---- epilogue ----
    if (widx == 2) {
        #pragma unroll
        for (int mp = 0; mp < 8; ++mp) {
            const int m0 = bm + wr * 128 + mp * 16 + quad * 4;
            const int bb = m0 >> 11;
            const int s0 = m0 & 2047;
            #pragma unroll
            for (int np = 0; np < 4; ++np) {
                const int col = bnl + wc * 64 + np * 16 + ln15;
                const float bvv = bias[col];
                ushort4 pk;
                pk.x = f2bf(acc[mp][np][0] + bvv);
                pk.y = f2bf(acc[mp][np][1] + bvv);
                pk.z = f2bf(acc[mp][np][2] + bvv);
                pk.w = f2bf(acc[mp][np][3] + bvv);
                *(ushort4*)(Vt + ((size_t)(bb * 16 + (col >> 7)) * 128 + (col & 127)) * SEQ + s0) = pk;
            }
        }
    } else {
        unsigned short* dst = widx ? Kb : Qb;
        #pragma unroll
        for (int mp = 0; mp < 8; ++mp)
            #pragma unroll
            for (int r = 0; r < 4; ++r) {
                const int row = bm + wr * 128 + mp * 16 + quad * 4 + r;
                #pragma unroll
                for (int np = 0; np < 4; ++np) {
                    const int col = bnl + wc * 64 + np * 16 + ln15;
                    dst[(size_t)row * DMODEL + col] = f2bf(acc[mp][np][r] + bias[col]);
                }
            }
    }
}

// ---------------------------------------------------------------------------
// Out-projection MFMA GEMM (fp32 out), m97 structure. (N=2048 -> only 128
// blocks at 256^2, so the 128^2 kernel keeps better CU balance here.)
// ---------------------------------------------------------------------------
__global__ __launch_bounds__(256) void gemm_out_kernel(
    const unsigned short* __restrict__ A, const unsigned short* __restrict__ Bt,
    const float* __restrict__ bias, float* __restrict__ C, int M, int N, int K)
{
    __shared__ __align__(16) unsigned short As[128 * 32];
    __shared__ __align__(16) unsigned short Bs[128 * 32];

    const int tid  = threadIdx.x;
    const int lane = tid & 63;
    const int wave = tid >> 6;
    const int ln15 = lane & 15;
    const int quad = lane >> 4;
    const int wm = (wave & 1) * 64;
    const int wn = (wave >> 1) * 64;
    const int bm = blockIdx.y * 128;
    const int bn = blockIdx.x * 128;

    const int srow = tid >> 2;
    const int scol = (tid & 3) * 8;

    const unsigned short* Ap = A  + (size_t)(bm + srow) * K + scol;
    const unsigned short* Bp = Bt + (size_t)(bn + srow) * K + scol;

    f32x4 acc[4][4];
    #pragma unroll
    for (int i = 0; i < 4; ++i)
        #pragma unroll
        for (int j = 0; j < 4; ++j) acc[i][j] = (f32x4){0.f, 0.f, 0.f, 0.f};

    for (int k0 = 0; k0 < K; k0 += 32) {
        __syncthreads();
        async_load16(Ap + k0,                    As + wave * 512);
        async_load16(Ap + (size_t)64 * K + k0,   As + 2048 + wave * 512);
        async_load16(Bp + k0,                    Bs + wave * 512);
        async_load16(Bp + (size_t)64 * K + k0,   Bs + 2048 + wave * 512);
        __syncthreads();

        short8 af[4], bf[4];
        #pragma unroll
        for (int mt = 0; mt < 4; ++mt)
            af[mt] = *(const short8*)(&As[(wm + mt * 16 + ln15) * 32 + quad * 8]);
        #pragma unroll
        for (int nt = 0; nt < 4; ++nt)
            bf[nt] = *(const short8*)(&Bs[(wn + nt * 16 + ln15) * 32 + quad * 8]);
        #pragma unroll
        for (int mt = 0; mt < 4; ++mt)
            #pragma unroll
            for (int nt = 0; nt < 4; ++nt)
                acc[mt][nt] = __builtin_amdgcn_mfma_f32_16x16x32_bf16(
                    af[mt], bf[nt], acc[mt][nt], 0, 0, 0);
    }

    #pragma unroll
    for (int mt = 0; mt < 4; ++mt)
        #pragma unroll
        for (int r = 0; r < 4; ++r) {
            const int row = bm + wm + mt * 16 + quad * 4 + r;
            #pragma unroll
            for (int nt = 0; nt < 4; ++nt) {
                const int col = bn + wn + nt * 16 + ln15;
                C[(size_t)row * N + col] = acc[mt][nt][r] + bias[col];
            }
        }
}

// ---------------------------------------------------------------------------
// MFMA flash attention — LDS-staged, double-buffered, pair-balanced,
// fast-path/diagonal split, XCD-pinned (blocks of one head ≡ same id mod 32
// -> same XCD under round-robin dispatch).
// ---------------------------------------------------------------------------
#define ATT_P_STRIDE 40

__global__ __launch_bounds__(256) void attn_kernel(
    const unsigned short* __restrict__ Qb, const unsigned short* __restrict__ Kb,
    const unsigned short* __restrict__ Vt,   // [B*H][HDIM][SEQ]
    unsigned short* __restrict__ O)
{
    __shared__ __align__(16) unsigned short Ks[2][32 * 128];
    __shared__ __align__(16) unsigned short Vs[2][128 * 32];
    __shared__ __align__(16) unsigned short Pl[4 * 16 * ATT_P_STRIDE];

    const int tid  = threadIdx.x;
    const int lane = tid & 63;
    const int wave = tid >> 6;
    const int ln15 = lane & 15;
    const int quad = lane >> 4;

    // XCD pinning: id = j*32 + g, g = head-group (b,h), j = q-pair index
    const int g = blockIdx.x & 31;
    const int jj = blockIdx.x >> 5;        // 0..15
    const int h = g & 15;
    const int b = g >> 4;

    const size_t rowbase = (size_t)b * SEQ;
    const size_t hoff    = (size_t)h * HDIM;
    const unsigned short* Kh  = Kb + rowbase * DMODEL + hoff;
    const unsigned short* Vth = Vt + (size_t)(b * NHEADS + h) * HDIM * SEQ;

    const float sc2     = 0.08838834764831845f * 1.4426950408889634f;
    const float slope2  = exp2f(-0.5f * (float)(h + 1)) * 1.4426950408889634f;
    const float slope16 = slope2 * 16.0f;
    const float slope32 = slope2 * 32.0f;

    // staging lane roles
    const int kq  = wave * 8 + (lane >> 4);
    const int ksl = lane & 15;
    const int dq  = wave * 32 + (lane >> 2);
    const int vsl = lane & 3;
    const int vsw = (ln15 >> 1) & 3;

    unsigned short* Pw = &Pl[wave * 16 * ATT_P_STRIDE];

    #pragma unroll 1
    for (int ph = 0; ph < 2; ++ph) {
        const int qblk = ph ? (31 - jj) : jj;
        const int q0w  = qblk * 64 + wave * 16;
        const int nT   = 2 * qblk + 2;

        short8 qf[4];
        {
            const unsigned short* qp =
                Qb + (rowbase + q0w + ln15) * DMODEL + hoff + quad * 8;
            qf[0] = *(const short8*)(qp);
            qf[1] = *(const short8*)(qp + 32);
            qf[2] = *(const short8*)(qp + 64);
            qf[3] = *(const short8*)(qp + 96);
        }

        f32x4 acc[8];
        #pragma unroll
        for (int nt = 0; nt < 8; ++nt) acc[nt] = (f32x4){0.f, 0.f, 0.f, 0.f};
        float lsum[4] = {0.f, 0.f, 0.f, 0.f};

        // incremental ALiBi bias: c0[r] = slope2*(kb+ln15 - (q0w+quad*4+r))
        float c0[4];
        {
            const float base = slope2 * (float)(ln15 - q0w - quad * 4);
            #pragma unroll
            for (int r = 0; r < 4; ++r) c0[r] = base - slope2 * (float)r;
        }

        // ---- stage tile 0 into buffer 0 ----
        #pragma unroll
        for (int i = 0; i < 2; ++i) {
            const int k = kq + i * 4;
            async_load16(Kh + (size_t)k * DMODEL + (ksl ^ (k & 15)) * 8,
                         &Ks[0][(wave * 8 + i * 4) * 128]);
        }
        #pragma unroll
        for (int i = 0; i < 2; ++i) {
            const int d = dq + i * 16;
            async_load16(Vth + (size_t)d * SEQ + (vsl ^ ((d >> 1) & 3)) * 8,
                         &Vs[0][(wave * 32 + i * 16) * 32]);
        }
        __syncthreads();

        for (int t = 0; t < nT; ++t) {
            const int kb  = t * 32;
            const int buf = t & 1;

            if (t + 1 < nT) {
                const int kb1 = kb + 32;
                #pragma unroll
                for (int i = 0; i < 2; ++i) {
                    const int k = kq + i * 4;
                    async_load16(Kh + (size_t)(kb1 + k) * DMODEL + (ksl ^ (k & 15)) * 8,
                                 &Ks[buf ^ 1][(wave * 8 + i * 4) * 128]);
                }
                #pragma unroll
                for (int i = 0; i < 2; ++i) {
                    const int d = dq + i * 16;
                    async_load16(Vth + (size_t)d * SEQ + kb1 + (vsl ^ ((d >> 1) & 3)) * 8,
                                 &Vs[buf ^ 1][(wave * 32 + i * 16) * 32]);
                }
            }

            if (kb <= q0w + 15) {
                const unsigned short* KsB = Ks[buf];
                const unsigned short* VsB = Vs[buf];

                f32x4 s0 = (f32x4){0.f,0.f,0.f,0.f}, s1 = (f32x4){0.f,0.f,0.f,0.f};
                #pragma unroll
                for (int c = 0; c < 4; ++c) {
                    const int slot = (c * 4 + quad) ^ ln15;
                    short8 kf0 = *(const short8*)(&KsB[ln15 * 128 + slot * 8]);
                    short8 kf1 = *(const short8*)(&KsB[(16 + ln15) * 128 + slot * 8]);
                    s0 = __builtin_amdgcn_mfma_f32_16x16x32_bf16(qf[c], kf0, s0, 0, 0, 0);
                    s1 = __builtin_amdgcn_mfma_f32_16x16x32_bf16(qf[c], kf1, s1, 0, 0, 0);
                }

                float p0[4], p1[4];
                if (kb + 31 <= q0w) {
                    // fully unmasked fast path
                    #pragma unroll
                    for (int r = 0; r < 4; ++r) {
                        p0[r] = exp2f(fmaf(s0[r], sc2, c0[r]));
                        p1[r] = exp2f(fmaf(s1[r], sc2, c0[r] + slope16));
                        lsum[r] += p0[r] + p1[r];
                    }
                } else {
                    // diagonal tile: per-element causal mask
                    #pragma unroll
                    for (int r = 0; r < 4; ++r) {
                        const int qrow = q0w + quad * 4 + r;
                        const int k0i = kb + ln15;
                        const float e0 = exp2f(fmaf(s0[r], sc2, c0[r]));
                        const float e1 = exp2f(fmaf(s1[r], sc2, c0[r] + slope16));
                        p0[r] = (k0i      <= qrow) ? e0 : 0.f;
                        p1[r] = (k0i + 16 <= qrow) ? e1 : 0.f;
                        lsum[r] += p0[r] + p1[r];
                    }
                }

                #pragma unroll
                for (int r = 0; r < 4; ++r) {
                    Pw[(quad * 4 + r) * ATT_P_STRIDE + ln15]      = f2bf(p0[r]);
                    Pw[(quad * 4 + r) * ATT_P_STRIDE + 16 + ln15] = f2bf(p1[r]);
                }
                __builtin_amdgcn_s_waitcnt(0xC07F);   // lgkmcnt(0)
                short8 pf = *(const short8*)(&Pw[ln15 * ATT_P_STRIDE + quad * 8]);

                #pragma unroll
                for (int nt = 0; nt < 8; ++nt) {
                    short8 vf = *(const short8*)(
                        &VsB[(nt * 16 + ln15) * 32 + (quad ^ vsw) * 8]);
                    acc[nt] = __builtin_amdgcn_mfma_f32_16x16x32_bf16(pf, vf, acc[nt], 0, 0, 0);
                }
            }

            #pragma unroll
            for (int r = 0; r < 4; ++r) c0[r] += slope32;
            __syncthreads();
        }

        #pragma unroll
        for (int r = 0; r < 4; ++r) {
            float l = lsum[r];
            l += __shfl_xor(l, 1, 64);
            l += __shfl_xor(l, 2, 64);
            l += __shfl_xor(l, 4, 64);
            l += __shfl_xor(l, 8, 64);
            const float inv = 1.0f / l;
            const size_t ob = (rowbase + q0w + quad * 4 + r) * DMODEL + hoff;
            #pragma unroll
            for (int nt = 0; nt < 8; ++nt)
                O[ob + nt * 16 + ln15] = f2bf(acc[nt][r] * inv);
        }
    }
}

// ---------------------------------------------------------------------------
extern "C" void kernel_launch(void* const* d_in, const int* in_sizes, int n_in,
                              void* d_out, int out_size, void* d_ws, size_t ws_size,
                              hipStream_t stream)
{
    const float* x  = (const float*)d_in[0];
    const float* wq = (const float*)d_in[1];
    const float* bq = (const float*)d_in[2];
    const float* wk = (const float*)d_in[3];
    const float* bk = (const float*)d_in[4];
    const float* wv = (const float*)d_in[5];
    const float* bv = (const float*)d_in[6];
    const float* wo = (const float*)d_in[7];
    const float* bo = (const float*)d_in[8];
    float* out = (float*)d_out;

    const size_t bufElems = (size_t)MROWS * DMODEL;   // 8.39M
    unsigned short* Qb  = (unsigned short*)d_ws;
    unsigned short* Kb  = Qb + bufElems;
    unsigned short* Vtg = Kb + bufElems;      // V^T: [B*H][HDIM][SEQ]
    unsigned short* xb  = Vtg + bufElems;     // x bf16; later reused as Ob
    unsigned short* Ob  = xb;                 // alias (xb dead after QKV GEMM)
    unsigned short* Wt  = xb + bufElems;      // 3 slots of 2048*2048 bf16

    const dim3 blk(256);

    convert_bf16_kernel<<<dim3((int)(bufElems / 1024)), blk, 0, stream>>>(
        x, xb, (int)bufElems);

    transpose3_bf16_kernel<<<dim3(32, 32, 3), blk, 0, stream>>>(wq, wk, wv, Wt);

    qkv_gemm256_kernel<<<dim3(24, 16), dim3(512), 0, stream>>>(
        xb, Wt, bq, bk, bv, Qb, Kb, Vtg);

    // wo -> Wt slot 0 (QKV GEMM has consumed it by stream order)
    transpose_bf16_kernel<<<dim3(32, 32), blk, 0, stream>>>(wo, Wt, DMODEL, DMODEL);

    attn_kernel<<<dim3(512), blk, 0, stream>>>(Qb, Kb, Vtg, Ob);

    gemm_out_kernel<<<dim3(16, 32), blk, 0, stream>>>(
        Ob, Wt, bo, out, MROWS, DMODEL, DMODEL);
}